// Round 3
// baseline (3275.261 us; speedup 1.0000x reference)
//
#include <hip/hip_runtime.h>
#include <hip/hip_bf16.h>

#define B_   64
#define T_   2048
#define IN_  256
#define H_   128
#define G_   512          // 4*H
#define M_   (B_ * T_)    // 131072

typedef _Float16 half2v __attribute__((ext_vector_type(2)));

#if defined(__has_builtin)
#if __has_builtin(__builtin_amdgcn_fdot2)
#define HAVE_FDOT2 1
#endif
#endif

__device__ __forceinline__ float dot2f(half2v a, half2v b, float c) {
#ifdef HAVE_FDOT2
    return __builtin_amdgcn_fdot2(a, b, c, false);
#else
    return c + (float)a.x * (float)b.x + (float)a.y * (float)b.y;
#endif
}
__device__ __forceinline__ half2v c2(float f) {
    return __builtin_bit_cast(half2v, f);
}
__device__ __forceinline__ float packh2(float a, float b) {
    half2v h; h.x = (_Float16)a; h.y = (_Float16)b;
    return __builtin_bit_cast(float, h);
}
__device__ __forceinline__ float bf2f(unsigned short u) {
    return __uint_as_float(((unsigned int)u) << 16);
}
// quad_perm DPP: xor1 = [1,0,3,2] = 0xB1, xor2 = [2,3,0,1] = 0x4E
__device__ __forceinline__ float dpp_xor1(float x) {
    int i = __float_as_int(x);
    return __int_as_float(__builtin_amdgcn_update_dpp(i, i, 0xB1, 0xF, 0xF, true));
}
__device__ __forceinline__ float dpp_xor2(float x) {
    int i = __float_as_int(x);
    return __int_as_float(__builtin_amdgcn_update_dpp(i, i, 0x4E, 0xF, 0xF, true));
}
#define L2E_  1.442695041f

// sigmoid(x) = 1/(1+2^(-x*log2e));  inf-safe, no clamp needed
__device__ __forceinline__ float fast_sigmoid(float x) {
    return __builtin_amdgcn_rcpf(1.f + __builtin_amdgcn_exp2f(-L2E_ * x));
}
__device__ __forceinline__ float fast_tanh(float x) {
    float y = __builtin_amdgcn_rcpf(1.f + __builtin_amdgcn_exp2f(-2.f * L2E_ * x));
    return fmaf(2.f, y, -1.f);
}

// ---------------------------------------------------------------------------
// K1: xp[dir][m][g] = x[m] . w_ih[dir][g] + b_ih[g] + b_hh[g]   (bf16 out)
// ---------------------------------------------------------------------------
__global__ __launch_bounds__(256) void gemm_in(
    const float* __restrict__ x,
    const float* __restrict__ w_f, const float* __restrict__ w_b,
    const float* __restrict__ bi_f, const float* __restrict__ bh_f,
    const float* __restrict__ bi_b, const float* __restrict__ bh_b,
    __hip_bfloat16* __restrict__ xp)
{
    const int m0  = blockIdx.x * 64;
    const int n0g = blockIdx.y * 64;
    const int dir = n0g >> 9;
    const int n0  = n0g & 511;
    const float* __restrict__ w  = dir ? w_b  : w_f;
    const float* __restrict__ bi = dir ? bi_b : bi_f;
    const float* __restrict__ bh = dir ? bh_b : bh_f;

    __shared__ float As[32][68];
    __shared__ float Bs[32][68];
    const int tid = threadIdx.x;
    const int tx = tid & 15, ty = tid >> 4;
    float acc[4][4] = {};

    for (int k0 = 0; k0 < 256; k0 += 32) {
        #pragma unroll
        for (int i = 0; i < 2; ++i) {
            int idx = i * 256 + tid;
            int row = idx >> 3;
            int kq  = idx & 7;
            float4 av = *reinterpret_cast<const float4*>(
                &x[(size_t)(m0 + row) * 256 + k0 + kq * 4]);
            As[kq*4+0][row] = av.x; As[kq*4+1][row] = av.y;
            As[kq*4+2][row] = av.z; As[kq*4+3][row] = av.w;
            float4 bv = *reinterpret_cast<const float4*>(
                &w[(size_t)(n0 + row) * 256 + k0 + kq * 4]);
            Bs[kq*4+0][row] = bv.x; Bs[kq*4+1][row] = bv.y;
            Bs[kq*4+2][row] = bv.z; Bs[kq*4+3][row] = bv.w;
        }
        __syncthreads();
        #pragma unroll
        for (int kk = 0; kk < 32; ++kk) {
            float4 a4 = *reinterpret_cast<const float4*>(&As[kk][ty * 4]);
            float4 b4 = *reinterpret_cast<const float4*>(&Bs[kk][tx * 4]);
            float av[4] = {a4.x, a4.y, a4.z, a4.w};
            float bv[4] = {b4.x, b4.y, b4.z, b4.w};
            #pragma unroll
            for (int i2 = 0; i2 < 4; ++i2)
                #pragma unroll
                for (int j = 0; j < 4; ++j)
                    acc[i2][j] += av[i2] * bv[j];
        }
        __syncthreads();
    }

    #pragma unroll
    for (int i2 = 0; i2 < 4; ++i2) {
        int m = m0 + ty * 4 + i2;
        #pragma unroll
        for (int j = 0; j < 4; ++j) {
            int n = n0 + tx * 4 + j;
            float v = acc[i2][j] + bi[n] + bh[n];
            xp[((size_t)dir * M_ + m) * G_ + n] = __float2bfloat16(v);
        }
    }
}

// ---------------------------------------------------------------------------
// K2: persistent recurrence. 128 WGs = (dir, batch); 512 threads.
// tid = j*4 + g. W row in 16 named float4 (fp16-packed). One RAW s_barrier
// per step (lgkmcnt-only drain — HBM prefetch stays in flight). Gate
// exchange via DPP quad_perm (VALU pipe). Prefetch depth 3.
// ---------------------------------------------------------------------------
__global__ __launch_bounds__(512, 2) void lstm_rec(
    const __hip_bfloat16* __restrict__ xp,   // [2][B][T][G]
    const float* __restrict__ w_hh_f,        // [G][H]
    const float* __restrict__ w_hh_b,
    __hip_bfloat16* __restrict__ hs)         // [B][T][2H]
{
    const int wg  = blockIdx.x;
    const int dir = wg >> 6;
    const int b   = wg & 63;
    const int tid = threadIdx.x;
    const int j   = tid >> 2;      // cell index 0..127
    const int g   = tid & 3;       // gate type (0=i,1=f,2=g,3=o)
    const int grow = g * H_ + j;   // row in [G]
    const float* __restrict__ w_hh = dir ? w_hh_b : w_hh_f;

    // ---- W row in 16 named float4 (64 VGPRs of packed fp16) ---------------
    const float4* wv4 = reinterpret_cast<const float4*>(w_hh + (size_t)grow * H_);
#define LOADW(q) float4 W##q; { float4 r0 = wv4[2*(q)], r1 = wv4[2*(q)+1]; \
    W##q.x = packh2(r0.x, r0.y); W##q.y = packh2(r0.z, r0.w); \
    W##q.z = packh2(r1.x, r1.y); W##q.w = packh2(r1.z, r1.w); }
    LOADW(0)  LOADW(1)  LOADW(2)  LOADW(3)
    LOADW(4)  LOADW(5)  LOADW(6)  LOADW(7)
    LOADW(8)  LOADW(9)  LOADW(10) LOADW(11)
    LOADW(12) LOADW(13) LOADW(14) LOADW(15)
#undef LOADW

    __shared__ alignas(16) _Float16 hbuf[2][H_];
    if (tid < H_) { hbuf[0][tid] = (_Float16)0.f; hbuf[1][tid] = (_Float16)0.f; }
    float c = 0.f;
    __syncthreads();

    const __hip_bfloat16* __restrict__ xb =
        xp + ((size_t)dir * B_ + b) * (size_t)T_ * G_;
    __hip_bfloat16* __restrict__ ho =
        hs + (size_t)b * T_ * (2 * H_) + dir * H_ + j;

    int t = dir ? (T_ - 1) : 0;
    const int dt = dir ? -1 : 1;

    // rolling prefetch, depth 3
    float g0 = bf2f(*reinterpret_cast<const unsigned short*>(&xb[(size_t)t * G_ + grow]));
    float g1 = bf2f(*reinterpret_cast<const unsigned short*>(&xb[(size_t)(t + dt) * G_ + grow]));
    float g2 = bf2f(*reinterpret_cast<const unsigned short*>(&xb[(size_t)(t + 2 * dt) * G_ + grow]));

    const float kk = (g == 2) ? (-2.f * L2E_) : (-L2E_);

    for (int s = 0; s < T_; ++s) {
        float g3 = 0.f;
        if (s + 3 < T_)
            g3 = bf2f(*reinterpret_cast<const unsigned short*>(
                &xb[(size_t)(t + 3 * dt) * G_ + grow]));

        const float4* hv4 = reinterpret_cast<const float4*>(hbuf[s & 1]);
        float a0 = g0, a1 = 0.f, a2 = 0.f, a3 = 0.f;
#define DOTQ(q) { float4 Hq = hv4[q]; \
        a0 = dot2f(c2(W##q.x), c2(Hq.x), a0); \
        a1 = dot2f(c2(W##q.y), c2(Hq.y), a1); \
        a2 = dot2f(c2(W##q.z), c2(Hq.z), a2); \
        a3 = dot2f(c2(W##q.w), c2(Hq.w), a3); }
        DOTQ(0)  DOTQ(1)  DOTQ(2)  DOTQ(3)
        DOTQ(4)  DOTQ(5)  DOTQ(6)  DOTQ(7)
        DOTQ(8)  DOTQ(9)  DOTQ(10) DOTQ(11)
        DOTQ(12) DOTQ(13) DOTQ(14) DOTQ(15)
#undef DOTQ
        float pre = (a0 + a1) + (a2 + a3);

        // activation: y = sigmoid(|k|*...) path; tanh = 2*sigmoid(2x)-1
        float y   = __builtin_amdgcn_rcpf(1.f + __builtin_amdgcn_exp2f(kk * pre));
        float act = (g == 2) ? fmaf(2.f, y, -1.f) : y;

        // quad gate exchange on the VALU pipe (DPP quad_perm)
        float e1 = dpp_xor1(act);
        float e2 = dpp_xor2(act);
        float e3 = dpp_xor1(e2);
        float si = (g==0)?act:(g==1)?e1:(g==2)?e2:e3;
        float sf = (g==1)?act:(g==0)?e1:(g==3)?e2:e3;
        float tg = (g==2)?act:(g==3)?e1:(g==0)?e2:e3;
        float so = (g==3)?act:(g==2)?e1:(g==1)?e2:e3;

        c = fmaf(sf, c, si * tg);
        float h = so * fast_tanh(c);

        if (g == 0) {
            hbuf[(s & 1) ^ 1][j] = (_Float16)h;
            ho[(size_t)t * (2 * H_)] = __float2bfloat16(h);
        }
        // drain LDS only; leave the HBM prefetches in flight across the barrier
        asm volatile("s_waitcnt lgkmcnt(0)\n\ts_barrier" ::: "memory");
        __builtin_amdgcn_sched_barrier(0);

        g0 = g1; g1 = g2; g2 = g3;
        t += dt;
    }
}

// ---------------------------------------------------------------------------
// K3: out[m][n] = hs[m] . mixer_w[n] + mixer_b[n]  (fp32 out)
// ---------------------------------------------------------------------------
__global__ __launch_bounds__(256) void mixer_gemm(
    const __hip_bfloat16* __restrict__ hs,   // [M][256]
    const float* __restrict__ mw,            // [256][256]
    const float* __restrict__ mb,
    float* __restrict__ out)                 // [M][256]
{
    const int m0 = blockIdx.x * 64;
    const int n0 = blockIdx.y * 64;
    __shared__ float As[32][68];
    __shared__ float Bs[32][68];
    const int tid = threadIdx.x;
    const int tx = tid & 15, ty = tid >> 4;
    float acc[4][4] = {};

    for (int k0 = 0; k0 < 256; k0 += 32) {
        #pragma unroll
        for (int i = 0; i < 2; ++i) {
            int idx = i * 256 + tid;
            int row = idx >> 3;
            int kq  = idx & 7;
            ushort4 a4 = *reinterpret_cast<const ushort4*>(
                &hs[(size_t)(m0 + row) * 256 + k0 + kq * 4]);
            As[kq*4+0][row] = bf2f(a4.x); As[kq*4+1][row] = bf2f(a4.y);
            As[kq*4+2][row] = bf2f(a4.z); As[kq*4+3][row] = bf2f(a4.w);
            float4 bv = *reinterpret_cast<const float4*>(
                &mw[(size_t)(n0 + row) * 256 + k0 + kq * 4]);
            Bs[kq*4+0][row] = bv.x; Bs[kq*4+1][row] = bv.y;
            Bs[kq*4+2][row] = bv.z; Bs[kq*4+3][row] = bv.w;
        }
        __syncthreads();
        #pragma unroll
        for (int kk = 0; kk < 32; ++kk) {
            float4 a4 = *reinterpret_cast<const float4*>(&As[kk][ty * 4]);
            float4 b4 = *reinterpret_cast<const float4*>(&Bs[kk][tx * 4]);
            float av[4] = {a4.x, a4.y, a4.z, a4.w};
            float bv[4] = {b4.x, b4.y, b4.z, b4.w};
            #pragma unroll
            for (int i2 = 0; i2 < 4; ++i2)
                #pragma unroll
                for (int j = 0; j < 4; ++j)
                    acc[i2][j] += av[i2] * bv[j];
        }
        __syncthreads();
    }

    #pragma unroll
    for (int i2 = 0; i2 < 4; ++i2) {
        int m = m0 + ty * 4 + i2;
        float4 o;
        o.x = acc[i2][0] + mb[n0 + tx * 4 + 0];
        o.y = acc[i2][1] + mb[n0 + tx * 4 + 1];
        o.z = acc[i2][2] + mb[n0 + tx * 4 + 2];
        o.w = acc[i2][3] + mb[n0 + tx * 4 + 3];
        *reinterpret_cast<float4*>(&out[(size_t)m * 256 + n0 + tx * 4]) = o;
    }
}

// ---------------------------------------------------------------------------
extern "C" void kernel_launch(void* const* d_in, const int* in_sizes, int n_in,
                              void* d_out, int out_size, void* d_ws, size_t ws_size,
                              hipStream_t stream) {
    const float* x       = (const float*)d_in[0];
    const float* w_ih_f  = (const float*)d_in[1];
    const float* w_hh_f  = (const float*)d_in[2];
    const float* b_ih_f  = (const float*)d_in[3];
    const float* b_hh_f  = (const float*)d_in[4];
    const float* w_ih_b  = (const float*)d_in[5];
    const float* w_hh_b  = (const float*)d_in[6];
    const float* b_ih_b  = (const float*)d_in[7];
    const float* b_hh_b  = (const float*)d_in[8];
    const float* mixer_w = (const float*)d_in[9];
    const float* mixer_b = (const float*)d_in[10];
    float* out = (float*)d_out;

    const size_t xp_bytes = (size_t)2 * M_ * G_ * sizeof(__hip_bfloat16); // 256 MiB
    const size_t hs_bytes = (size_t)M_ * 2 * H_ * sizeof(__hip_bfloat16); //  64 MiB
    if (ws_size < xp_bytes + hs_bytes) return;

    __hip_bfloat16* xp = (__hip_bfloat16*)d_ws;
    __hip_bfloat16* hs = (__hip_bfloat16*)((char*)d_ws + xp_bytes);

    gemm_in<<<dim3(M_ / 64, 1024 / 64), 256, 0, stream>>>(
        x, w_ih_f, w_ih_b, b_ih_f, b_hh_f, b_ih_b, b_hh_b, xp);
    lstm_rec<<<128, 512, 0, stream>>>(xp, w_hh_f, w_hh_b, hs);
    mixer_gemm<<<dim3(M_ / 64, 256 / 64), 256, 0, stream>>>(
        hs, mixer_w, mixer_b, out);
}

// Round 4
// 2508.835 us; speedup vs baseline: 1.3055x; 1.3055x over previous
//
#include <hip/hip_runtime.h>
#include <hip/hip_bf16.h>

#define B_   64
#define T_   2048
#define IN_  256
#define H_   128
#define G_   512          // 4*H
#define M_   (B_ * T_)    // 131072

typedef _Float16 half2v __attribute__((ext_vector_type(2)));

#if defined(__has_builtin)
#if __has_builtin(__builtin_amdgcn_fdot2)
#define HAVE_FDOT2 1
#endif
#endif

__device__ __forceinline__ float dot2f(half2v a, half2v b, float c) {
#ifdef HAVE_FDOT2
    return __builtin_amdgcn_fdot2(a, b, c, false);
#else
    return c + (float)a.x * (float)b.x + (float)a.y * (float)b.y;
#endif
}
__device__ __forceinline__ float bf2f(unsigned int u) {
    return __uint_as_float(u << 16);
}
// quad_perm DPP: xor1 = [1,0,3,2] = 0xB1, xor2 = [2,3,0,1] = 0x4E
__device__ __forceinline__ float dpp_xor1(float x) {
    int i = __float_as_int(x);
    return __int_as_float(__builtin_amdgcn_update_dpp(i, i, 0xB1, 0xF, 0xF, true));
}
__device__ __forceinline__ float dpp_xor2(float x) {
    int i = __float_as_int(x);
    return __int_as_float(__builtin_amdgcn_update_dpp(i, i, 0x4E, 0xF, 0xF, true));
}
#define L2E_  1.442695041f

__device__ __forceinline__ float fast_tanh(float x) {
    float y = __builtin_amdgcn_rcpf(1.f + __builtin_amdgcn_exp2f(-2.f * L2E_ * x));
    return fmaf(2.f, y, -1.f);
}

// ---------------------------------------------------------------------------
// K1: xp_perm[dir][m][Q*4+g] = x[m].w_ih[dir][g*128+Q] + b_ih + b_hh  (bf16)
// Inner layout permuted so the 4 gates of cell Q are contiguous (8B/lane in K2).
// ---------------------------------------------------------------------------
__global__ __launch_bounds__(256) void gemm_in(
    const float* __restrict__ x,
    const float* __restrict__ w_f, const float* __restrict__ w_b,
    const float* __restrict__ bi_f, const float* __restrict__ bh_f,
    const float* __restrict__ bi_b, const float* __restrict__ bh_b,
    __hip_bfloat16* __restrict__ xp)
{
    const int m0  = blockIdx.x * 64;
    const int n0g = blockIdx.y * 64;
    const int dir = n0g >> 9;
    const int n0  = n0g & 511;
    const float* __restrict__ w  = dir ? w_b  : w_f;
    const float* __restrict__ bi = dir ? bi_b : bi_f;
    const float* __restrict__ bh = dir ? bh_b : bh_f;

    __shared__ float As[32][68];
    __shared__ float Bs[32][68];
    const int tid = threadIdx.x;
    const int tx = tid & 15, ty = tid >> 4;
    float acc[4][4] = {};

    for (int k0 = 0; k0 < 256; k0 += 32) {
        #pragma unroll
        for (int i = 0; i < 2; ++i) {
            int idx = i * 256 + tid;
            int row = idx >> 3;
            int kq  = idx & 7;
            float4 av = *reinterpret_cast<const float4*>(
                &x[(size_t)(m0 + row) * 256 + k0 + kq * 4]);
            As[kq*4+0][row] = av.x; As[kq*4+1][row] = av.y;
            As[kq*4+2][row] = av.z; As[kq*4+3][row] = av.w;
            float4 bv = *reinterpret_cast<const float4*>(
                &w[(size_t)(n0 + row) * 256 + k0 + kq * 4]);
            Bs[kq*4+0][row] = bv.x; Bs[kq*4+1][row] = bv.y;
            Bs[kq*4+2][row] = bv.z; Bs[kq*4+3][row] = bv.w;
        }
        __syncthreads();
        #pragma unroll
        for (int kk = 0; kk < 32; ++kk) {
            float4 a4 = *reinterpret_cast<const float4*>(&As[kk][ty * 4]);
            float4 b4 = *reinterpret_cast<const float4*>(&Bs[kk][tx * 4]);
            float av[4] = {a4.x, a4.y, a4.z, a4.w};
            float bv[4] = {b4.x, b4.y, b4.z, b4.w};
            #pragma unroll
            for (int i2 = 0; i2 < 4; ++i2)
                #pragma unroll
                for (int j = 0; j < 4; ++j)
                    acc[i2][j] += av[i2] * bv[j];
        }
        __syncthreads();
    }

    #pragma unroll
    for (int i2 = 0; i2 < 4; ++i2) {
        int m = m0 + ty * 4 + i2;
        #pragma unroll
        for (int j = 0; j < 4; ++j) {
            int n = n0 + tx * 4 + j;
            float v = acc[i2][j] + bi[n] + bh[n];
            int q = n & 127, g = n >> 7;                 // permuted inner index
            xp[((size_t)dir * M_ + m) * G_ + q * 4 + g] = __float2bfloat16(v);
        }
    }
}

// ---------------------------------------------------------------------------
// K2: persistent recurrence, K-split layout. 128 WGs = (dir,b); 512 threads.
// tid = Q*4 + s : Q = cell 0..127, s = K-chunk 0..3 ([s*32, s*32+32)).
// Each lane: 4 gate rows (g*128+Q) over its 32-wide K-chunk = 64 dot2;
// h read = 64B/lane (4x less LDS return traffic than full-K layout).
// Quad DPP butterfly sums partials over s; one raw lgkm-barrier per step;
// xp prefetched 4 steps ahead in statically-named regs (stays in flight).
// ---------------------------------------------------------------------------
__global__ __launch_bounds__(512, 2) void lstm_rec(
    const __hip_bfloat16* __restrict__ xp,   // [2][B][T][128][4] (Q,g inner)
    const float* __restrict__ w_hh_f,        // [G][H]
    const float* __restrict__ w_hh_b,
    __hip_bfloat16* __restrict__ hs)         // [B][T][2H]
{
    const int wg  = blockIdx.x;
    const int dir = wg >> 6;
    const int b   = wg & 63;
    const int tid = threadIdx.x;
    const int s   = tid & 3;       // K-chunk
    const int Q   = tid >> 2;      // cell
    const float* __restrict__ w_hh = dir ? w_hh_b : w_hh_f;

    // ---- W: rows g*128+Q, K-chunk s*32..s*32+31, packed half2 (64 VGPR) ---
    half2v Wr[4][16];
    #pragma unroll
    for (int g = 0; g < 4; ++g) {
        const float* wrow = w_hh + (size_t)(g * H_ + Q) * H_ + s * 32;
        #pragma unroll
        for (int k = 0; k < 16; ++k) {
            half2v hv; hv.x = (_Float16)wrow[2*k]; hv.y = (_Float16)wrow[2*k+1];
            Wr[g][k] = hv;
        }
    }

    __shared__ alignas(16) _Float16 hbuf[2][H_];
    if (tid < 2 * H_) (&hbuf[0][0])[tid] = (_Float16)0.f;
    float c = 0.f;
    __syncthreads();

    const unsigned short* __restrict__ xb =
        reinterpret_cast<const unsigned short*>(xp) + ((size_t)(dir * B_ + b)) * T_ * G_;
    __hip_bfloat16* __restrict__ ho =
        hs + (size_t)b * T_ * (2 * H_) + dir * H_ + Q;

    int t = dir ? (T_ - 1) : 0;
    const int dt = dir ? -1 : 1;
    const float kk = (s == 2) ? (-2.f * L2E_) : (-L2E_);

    // prologue: load steps 0..3
    uint2 cur[4], nxt[4];
    #pragma unroll
    for (int i = 0; i < 4; ++i) {
        int tt = dir ? (T_ - 1 - i) : i;
        cur[i] = *reinterpret_cast<const uint2*>(xb + (size_t)tt * G_ + Q * 4);
    }

    for (int blk = 0; blk < T_ / 4; ++blk) {
        // issue next 4 prefetches (consumed next block; no vmcnt drain at barriers)
        #pragma unroll
        for (int i = 0; i < 4; ++i) {
            int sp = blk * 4 + 4 + i; if (sp > T_ - 1) sp = T_ - 1;
            int tt = dir ? (T_ - 1 - sp) : sp;
            nxt[i] = *reinterpret_cast<const uint2*>(xb + (size_t)tt * G_ + Q * 4);
        }

        #pragma unroll
        for (int i = 0; i < 4; ++i) {
            const _Float16* hp = hbuf[i & 1];
            // 4 x ds_read_b128: this lane's 32-half K-chunk
            uint4 u0 = *reinterpret_cast<const uint4*>(hp + s * 32 + 0);
            uint4 u1 = *reinterpret_cast<const uint4*>(hp + s * 32 + 8);
            uint4 u2 = *reinterpret_cast<const uint4*>(hp + s * 32 + 16);
            uint4 u3 = *reinterpret_cast<const uint4*>(hp + s * 32 + 24);
            unsigned int hu[16] = {u0.x,u0.y,u0.z,u0.w, u1.x,u1.y,u1.z,u1.w,
                                   u2.x,u2.y,u2.z,u2.w, u3.x,u3.y,u3.z,u3.w};
            float p0 = 0.f, p1 = 0.f, p2 = 0.f, p3 = 0.f;
            #pragma unroll
            for (int k = 0; k < 16; ++k) {
                half2v hk = __builtin_bit_cast(half2v, hu[k]);
                p0 = dot2f(Wr[0][k], hk, p0);
                p1 = dot2f(Wr[1][k], hk, p1);
                p2 = dot2f(Wr[2][k], hk, p2);
                p3 = dot2f(Wr[3][k], hk, p3);
            }
            // butterfly over s (quad): every lane gets full 4-gate sums
            p0 += dpp_xor1(p0); p0 += dpp_xor2(p0);
            p1 += dpp_xor1(p1); p1 += dpp_xor2(p1);
            p2 += dpp_xor1(p2); p2 += dpp_xor2(p2);
            p3 += dpp_xor1(p3); p3 += dpp_xor2(p3);

            // lane s handles gate s: add xp and activate
            float psel = (s == 0) ? p0 : (s == 1) ? p1 : (s == 2) ? p2 : p3;
            unsigned int wsel = (s & 2) ? cur[i].y : cur[i].x;
            unsigned int g16  = (s & 1) ? (wsel >> 16) : (wsel & 0xffffu);
            float pre = psel + bf2f(g16);
            float y   = __builtin_amdgcn_rcpf(1.f + __builtin_amdgcn_exp2f(kk * pre));
            float act = (s == 2) ? fmaf(2.f, y, -1.f) : y;

            // exchange activated gates within quad
            float e1 = dpp_xor1(act);
            float e2 = dpp_xor2(act);
            float e3 = dpp_xor1(e2);
            float si = (s==0)?act:(s==1)?e1:(s==2)?e2:e3;
            float sf = (s==1)?act:(s==0)?e1:(s==3)?e2:e3;
            float tg = (s==2)?act:(s==3)?e1:(s==0)?e2:e3;
            float so = (s==3)?act:(s==2)?e1:(s==1)?e2:e3;

            c = fmaf(sf, c, si * tg);
            float h = so * fast_tanh(c);

            if (s == 0) {
                hbuf[(i & 1) ^ 1][Q] = (_Float16)h;
                ho[(size_t)t * (2 * H_)] = __float2bfloat16(h);
            }
            // drain LDS only; HBM prefetches stay in flight across the barrier
            asm volatile("s_waitcnt lgkmcnt(0)" ::: "memory");
            __builtin_amdgcn_s_barrier();
            t += dt;
        }

        #pragma unroll
        for (int i = 0; i < 4; ++i) cur[i] = nxt[i];
    }
}

// ---------------------------------------------------------------------------
// K3: out[m][n] = hs[m] . mixer_w[n] + mixer_b[n]  (fp32 out)
// ---------------------------------------------------------------------------
__global__ __launch_bounds__(256) void mixer_gemm(
    const __hip_bfloat16* __restrict__ hs,   // [M][256]
    const float* __restrict__ mw,            // [256][256]
    const float* __restrict__ mb,
    float* __restrict__ out)                 // [M][256]
{
    const int m0 = blockIdx.x * 64;
    const int n0 = blockIdx.y * 64;
    __shared__ float As[32][68];
    __shared__ float Bs[32][68];
    const int tid = threadIdx.x;
    const int tx = tid & 15, ty = tid >> 4;
    float acc[4][4] = {};

    for (int k0 = 0; k0 < 256; k0 += 32) {
        #pragma unroll
        for (int i = 0; i < 2; ++i) {
            int idx = i * 256 + tid;
            int row = idx >> 3;
            int kq  = idx & 7;
            ushort4 a4 = *reinterpret_cast<const ushort4*>(
                &hs[(size_t)(m0 + row) * 256 + k0 + kq * 4]);
            As[kq*4+0][row] = bf2f(a4.x); As[kq*4+1][row] = bf2f(a4.y);
            As[kq*4+2][row] = bf2f(a4.z); As[kq*4+3][row] = bf2f(a4.w);
            float4 bv = *reinterpret_cast<const float4*>(
                &mw[(size_t)(n0 + row) * 256 + k0 + kq * 4]);
            Bs[kq*4+0][row] = bv.x; Bs[kq*4+1][row] = bv.y;
            Bs[kq*4+2][row] = bv.z; Bs[kq*4+3][row] = bv.w;
        }
        __syncthreads();
        #pragma unroll
        for (int kk = 0; kk < 32; ++kk) {
            float4 a4 = *reinterpret_cast<const float4*>(&As[kk][ty * 4]);
            float4 b4 = *reinterpret_cast<const float4*>(&Bs[kk][tx * 4]);
            float av[4] = {a4.x, a4.y, a4.z, a4.w};
            float bv[4] = {b4.x, b4.y, b4.z, b4.w};
            #pragma unroll
            for (int i2 = 0; i2 < 4; ++i2)
                #pragma unroll
                for (int j = 0; j < 4; ++j)
                    acc[i2][j] += av[i2] * bv[j];
        }
        __syncthreads();
    }

    #pragma unroll
    for (int i2 = 0; i2 < 4; ++i2) {
        int m = m0 + ty * 4 + i2;
        float4 o;
        o.x = acc[i2][0] + mb[n0 + tx * 4 + 0];
        o.y = acc[i2][1] + mb[n0 + tx * 4 + 1];
        o.z = acc[i2][2] + mb[n0 + tx * 4 + 2];
        o.w = acc[i2][3] + mb[n0 + tx * 4 + 3];
        *reinterpret_cast<float4*>(&out[(size_t)m * 256 + n0 + tx * 4]) = o;
    }
}

// ---------------------------------------------------------------------------
extern "C" void kernel_launch(void* const* d_in, const int* in_sizes, int n_in,
                              void* d_out, int out_size, void* d_ws, size_t ws_size,
                              hipStream_t stream) {
    const float* x       = (const float*)d_in[0];
    const float* w_ih_f  = (const float*)d_in[1];
    const float* w_hh_f  = (const float*)d_in[2];
    const float* b_ih_f  = (const float*)d_in[3];
    const float* b_hh_f  = (const float*)d_in[4];
    const float* w_ih_b  = (const float*)d_in[5];
    const float* w_hh_b  = (const float*)d_in[6];
    const float* b_ih_b  = (const float*)d_in[7];
    const float* b_hh_b  = (const float*)d_in[8];
    const float* mixer_w = (const float*)d_in[9];
    const float* mixer_b = (const float*)d_in[10];
    float* out = (float*)d_out;

    const size_t xp_bytes = (size_t)2 * M_ * G_ * sizeof(__hip_bfloat16); // 256 MiB
    const size_t hs_bytes = (size_t)M_ * 2 * H_ * sizeof(__hip_bfloat16); //  64 MiB
    if (ws_size < xp_bytes + hs_bytes) return;

    __hip_bfloat16* xp = (__hip_bfloat16*)d_ws;
    __hip_bfloat16* hs = (__hip_bfloat16*)((char*)d_ws + xp_bytes);

    gemm_in<<<dim3(M_ / 64, 1024 / 64), 256, 0, stream>>>(
        x, w_ih_f, w_ih_b, b_ih_f, b_hh_f, b_ih_b, b_hh_b, xp);
    lstm_rec<<<128, 512, 0, stream>>>(xp, w_hh_f, w_hh_b, hs);
    mixer_gemm<<<dim3(M_ / 64, 256 / 64), 256, 0, stream>>>(
        hs, mixer_w, mixer_b, out);
}

// Round 5
// 1526.312 us; speedup vs baseline: 2.1459x; 1.6437x over previous
//
#include <hip/hip_runtime.h>
#include <hip/hip_bf16.h>

#define B_   64
#define T_   2048
#define IN_  256
#define H_   128
#define G_   512          // 4*H
#define M_   (B_ * T_)    // 131072

typedef _Float16 half2v __attribute__((ext_vector_type(2)));
typedef __bf16 bf16x8 __attribute__((ext_vector_type(8)));
typedef float f32x4 __attribute__((ext_vector_type(4)));
typedef unsigned short u16x8 __attribute__((ext_vector_type(8)));

#define L2E_  1.442695041f

__device__ __forceinline__ float dot2f(half2v a, half2v b, float c) {
    return __builtin_amdgcn_fdot2(a, b, c, false);
}
__device__ __forceinline__ half2v mk2(float a, float b) {
    half2v h; h.x = (_Float16)a; h.y = (_Float16)b; return h;
}
__device__ __forceinline__ unsigned short f2bf(float f) {   // RNE fp32->bf16
    unsigned u = __float_as_uint(f);
    return (unsigned short)((u + 0x7fffu + ((u >> 16) & 1u)) >> 16);
}
__device__ __forceinline__ float dpp_xor1(float x) {
    int i = __float_as_int(x);
    return __int_as_float(__builtin_amdgcn_update_dpp(i, i, 0xB1, 0xF, 0xF, true));
}
__device__ __forceinline__ float dpp_xor2(float x) {
    int i = __float_as_int(x);
    return __int_as_float(__builtin_amdgcn_update_dpp(i, i, 0x4E, 0xF, 0xF, true));
}
__device__ __forceinline__ float sigp(float x) {
    return __builtin_amdgcn_rcpf(1.f + __builtin_amdgcn_exp2f(-L2E_ * x));
}
__device__ __forceinline__ float tanhp(float x) {
    return fmaf(2.f, __builtin_amdgcn_rcpf(1.f + __builtin_amdgcn_exp2f(-2.f * L2E_ * x)), -1.f);
}

// ---------------------------------------------------------------------------
// K1: bf16 MFMA GEMM.  xp[dir][m][q*4+g] = x[m].w_ih[dir][g*128+q] + biases
// tile 64(M) x 64(N'), K=256 in 4 stages of 64. 4 waves, each a 32x32 quadrant.
// B tile rows gathered as r=(q-q0)*4+g so the output is contiguous in q*4+g.
// ---------------------------------------------------------------------------
__global__ __launch_bounds__(256) void gemm_in_mfma(
    const float* __restrict__ x,
    const float* __restrict__ w_f, const float* __restrict__ w_b,
    const float* __restrict__ bi_f, const float* __restrict__ bh_f,
    const float* __restrict__ bi_b, const float* __restrict__ bh_b,
    __hip_bfloat16* __restrict__ xp)
{
    const int nt  = blockIdx.x;          // 0..15
    const int m0  = blockIdx.y * 64;
    const int dir = nt >> 3;
    const int q0  = (nt & 7) * 16;
    const float* __restrict__ w  = dir ? w_b  : w_f;
    const float* __restrict__ bi = dir ? bi_b : bi_f;
    const float* __restrict__ bh = dir ? bh_b : bh_f;

    __shared__ alignas(16) unsigned short Asm[64 * 64];
    __shared__ alignas(16) unsigned short Bsm[64 * 64];
    __shared__ float bias_s[64];

    const int tid = threadIdx.x;
    const int wv  = tid >> 6;
    const int ln  = tid & 63;
    const int wr  = (wv >> 1) * 32;
    const int wc  = (wv & 1) * 32;
    const int l15 = ln & 15;
    const int l4  = ln >> 4;

#define STAGE_A(c2, k0) { int row = (c2) >> 3, kc = (c2) & 7; \
    const float4* sp = reinterpret_cast<const float4*>(x + (size_t)(m0 + row) * 256 + (k0) + kc * 8); \
    float4 fa = sp[0], fb = sp[1]; \
    u16x8 pk; pk[0]=f2bf(fa.x); pk[1]=f2bf(fa.y); pk[2]=f2bf(fa.z); pk[3]=f2bf(fa.w); \
    pk[4]=f2bf(fb.x); pk[5]=f2bf(fb.y); pk[6]=f2bf(fb.z); pk[7]=f2bf(fb.w); \
    *reinterpret_cast<u16x8*>(reinterpret_cast<char*>(Asm) + row * 128 + ((kc * 16) ^ ((row & 7) << 4))) = pk; }

#define STAGE_B(c2, k0) { int row = (c2) >> 3, kc = (c2) & 7; \
    int nglob = (row & 3) * 128 + q0 + (row >> 2); \
    const float4* sp = reinterpret_cast<const float4*>(w + (size_t)nglob * 256 + (k0) + kc * 8); \
    float4 fa = sp[0], fb = sp[1]; \
    u16x8 pk; pk[0]=f2bf(fa.x); pk[1]=f2bf(fa.y); pk[2]=f2bf(fa.z); pk[3]=f2bf(fa.w); \
    pk[4]=f2bf(fb.x); pk[5]=f2bf(fb.y); pk[6]=f2bf(fb.z); pk[7]=f2bf(fb.w); \
    *reinterpret_cast<u16x8*>(reinterpret_cast<char*>(Bsm) + row * 128 + ((kc * 16) ^ ((row & 7) << 4))) = pk; }

#define FRAG(BASE, rowe, kb) \
    __builtin_bit_cast(bf16x8, *reinterpret_cast<const uint4*>( \
        reinterpret_cast<const char*>(BASE) + (rowe) * 128 + ((kb) ^ (((rowe) & 7) << 4))))

    STAGE_A(tid, 0)  STAGE_A(tid + 256, 0)
    STAGE_B(tid, 0)  STAGE_B(tid + 256, 0)
    if (tid < 64) {
        int n = (tid & 3) * 128 + q0 + (tid >> 2);
        bias_s[tid] = bi[n] + bh[n];
    }
    __syncthreads();

    const float bv0 = bias_s[wc + l15];
    const float bv1 = bias_s[wc + 16 + l15];
    f32x4 acc00 = {bv0, bv0, bv0, bv0};
    f32x4 acc01 = {bv1, bv1, bv1, bv1};
    f32x4 acc10 = {bv0, bv0, bv0, bv0};
    f32x4 acc11 = {bv1, bv1, bv1, bv1};

    const int ra0 = wr + l15,      ra1 = wr + 16 + l15;
    const int rb0 = wc + l15,      rb1 = wc + 16 + l15;

    for (int kst = 0; kst < 4; ++kst) {
        if (kst) {
            __syncthreads();
            STAGE_A(tid, kst * 64)  STAGE_A(tid + 256, kst * 64)
            STAGE_B(tid, kst * 64)  STAGE_B(tid + 256, kst * 64)
            __syncthreads();
        }
        #pragma unroll
        for (int ks = 0; ks < 64; ks += 32) {
            int kb = ks * 2 + (l4 << 4);
            bf16x8 a0 = FRAG(Asm, ra0, kb);
            bf16x8 a1 = FRAG(Asm, ra1, kb);
            bf16x8 b0 = FRAG(Bsm, rb0, kb);
            bf16x8 b1 = FRAG(Bsm, rb1, kb);
            acc00 = __builtin_amdgcn_mfma_f32_16x16x32_bf16(a0, b0, acc00, 0, 0, 0);
            acc01 = __builtin_amdgcn_mfma_f32_16x16x32_bf16(a0, b1, acc01, 0, 0, 0);
            acc10 = __builtin_amdgcn_mfma_f32_16x16x32_bf16(a1, b0, acc10, 0, 0, 0);
            acc11 = __builtin_amdgcn_mfma_f32_16x16x32_bf16(a1, b1, acc11, 0, 0, 0);
        }
    }
    __syncthreads();

#define DWRITE(accv, mi, ni) { int row = wr + (mi) * 16 + l4 * 4; int col = wc + (ni) * 16 + l15; \
    Asm[(row + 0) * 64 + col] = f2bf(accv[0]); Asm[(row + 1) * 64 + col] = f2bf(accv[1]); \
    Asm[(row + 2) * 64 + col] = f2bf(accv[2]); Asm[(row + 3) * 64 + col] = f2bf(accv[3]); }
    DWRITE(acc00, 0, 0) DWRITE(acc01, 0, 1) DWRITE(acc10, 1, 0) DWRITE(acc11, 1, 1)
#undef DWRITE
    __syncthreads();

    #pragma unroll
    for (int p = 0; p < 2; ++p) {
        int c2 = tid + p * 256;
        int row = c2 >> 3, ch = c2 & 7;
        uint4 v = *reinterpret_cast<const uint4*>(reinterpret_cast<const char*>(Asm) + row * 128 + ch * 16);
        *reinterpret_cast<uint4*>(xp + ((size_t)dir * M_ + m0 + row) * G_ + q0 * 4 + ch * 8) = v;
    }
#undef STAGE_A
#undef STAGE_B
}

// ---------------------------------------------------------------------------
// K2: persistent recurrence. 128 WGs=(dir,b); 512 thr: tid=Q*4+s.
// ALL per-thread state in named scalars (no arrays -> no LDS promotion).
// After the p-butterfly every lane has all 4 gate sums: each lane computes
// all activations redundantly (no second cross-lane round).
// ---------------------------------------------------------------------------
__global__ __launch_bounds__(512, 2) void lstm_rec(
    const __hip_bfloat16* __restrict__ xp,   // [2][B][T][128][4]
    const float* __restrict__ w_hh_f,        // [G][H]
    const float* __restrict__ w_hh_b,
    __hip_bfloat16* __restrict__ hs)         // [B][T][2H]
{
    const int wg  = blockIdx.x;
    const int dir = wg >> 6;
    const int b   = wg & 63;
    const int tid = threadIdx.x;
    const int s   = tid & 3;
    const int Q   = tid >> 2;
    const float* __restrict__ w_hh = dir ? w_hh_b : w_hh_f;

#define DECLW(g) half2v W##g##_0,W##g##_1,W##g##_2,W##g##_3,W##g##_4,W##g##_5,W##g##_6,W##g##_7, \
    W##g##_8,W##g##_9,W##g##_10,W##g##_11,W##g##_12,W##g##_13,W##g##_14,W##g##_15
    DECLW(0); DECLW(1); DECLW(2); DECLW(3);
#undef DECLW
#define LOADW(g) { const float4* p = reinterpret_cast<const float4*>(w_hh + (size_t)((g) * H_ + Q) * H_ + s * 32); \
    float4 r0=p[0],r1=p[1],r2=p[2],r3=p[3],r4=p[4],r5=p[5],r6=p[6],r7=p[7]; \
    W##g##_0=mk2(r0.x,r0.y);  W##g##_1=mk2(r0.z,r0.w);  W##g##_2=mk2(r1.x,r1.y);  W##g##_3=mk2(r1.z,r1.w); \
    W##g##_4=mk2(r2.x,r2.y);  W##g##_5=mk2(r2.z,r2.w);  W##g##_6=mk2(r3.x,r3.y);  W##g##_7=mk2(r3.z,r3.w); \
    W##g##_8=mk2(r4.x,r4.y);  W##g##_9=mk2(r4.z,r4.w);  W##g##_10=mk2(r5.x,r5.y); W##g##_11=mk2(r5.z,r5.w); \
    W##g##_12=mk2(r6.x,r6.y); W##g##_13=mk2(r6.z,r6.w); W##g##_14=mk2(r7.x,r7.y); W##g##_15=mk2(r7.z,r7.w); }
    LOADW(0) LOADW(1) LOADW(2) LOADW(3)
#undef LOADW

    __shared__ alignas(16) _Float16 hbuf[2][H_];
    if (tid < 2 * H_) (&hbuf[0][0])[tid] = (_Float16)0.f;
    float c = 0.f;
    __syncthreads();

    const unsigned short* __restrict__ xb =
        reinterpret_cast<const unsigned short*>(xp) + ((size_t)(dir * B_ + b)) * T_ * G_;
    __hip_bfloat16* __restrict__ ho =
        hs + (size_t)b * T_ * (2 * H_) + dir * H_ + Q;

    int t = dir ? (T_ - 1) : 0;
    const int dt = dir ? -1 : 1;

#define XPLD(sp) (*reinterpret_cast<const uint2*>(xb + (size_t)(dir ? (T_ - 1 - (sp)) : (sp)) * G_ + Q * 4))
    uint2 cur0 = XPLD(0), cur1 = XPLD(1), cur2 = XPLD(2), cur3 = XPLD(3);

#define DOT1(hw, k) { half2v hh = __builtin_bit_cast(half2v, hw); \
    p0 = dot2f(W0_##k, hh, p0); p1 = dot2f(W1_##k, hh, p1); \
    p2 = dot2f(W2_##k, hh, p2); p3 = dot2f(W3_##k, hh, p3); }

#define STEP(par, CUR) { \
    const _Float16* hp = hbuf[par]; \
    uint4 u0 = *reinterpret_cast<const uint4*>(hp + s * 32); \
    uint4 u1 = *reinterpret_cast<const uint4*>(hp + s * 32 + 8); \
    uint4 u2 = *reinterpret_cast<const uint4*>(hp + s * 32 + 16); \
    uint4 u3 = *reinterpret_cast<const uint4*>(hp + s * 32 + 24); \
    float p0 = 0.f, p1 = 0.f, p2 = 0.f, p3 = 0.f; \
    DOT1(u0.x, 0)  DOT1(u0.y, 1)  DOT1(u0.z, 2)  DOT1(u0.w, 3) \
    DOT1(u1.x, 4)  DOT1(u1.y, 5)  DOT1(u1.z, 6)  DOT1(u1.w, 7) \
    DOT1(u2.x, 8)  DOT1(u2.y, 9)  DOT1(u2.z, 10) DOT1(u2.w, 11) \
    DOT1(u3.x, 12) DOT1(u3.y, 13) DOT1(u3.z, 14) DOT1(u3.w, 15) \
    p0 += dpp_xor1(p0); p0 += dpp_xor2(p0); \
    p1 += dpp_xor1(p1); p1 += dpp_xor2(p1); \
    p2 += dpp_xor1(p2); p2 += dpp_xor2(p2); \
    p3 += dpp_xor1(p3); p3 += dpp_xor2(p3); \
    float xi = __uint_as_float(CUR.x << 16); \
    float xf = __uint_as_float(CUR.x & 0xffff0000u); \
    float xg = __uint_as_float(CUR.y << 16); \
    float xo = __uint_as_float(CUR.y & 0xffff0000u); \
    float si = sigp(p0 + xi), sf = sigp(p1 + xf); \
    float tg = tanhp(p2 + xg), so = sigp(p3 + xo); \
    c = fmaf(sf, c, si * tg); \
    float h = so * tanhp(c); \
    if (s == 0) { \
        hbuf[(par) ^ 1][Q] = (_Float16)h; \
        ho[(size_t)t * (2 * H_)] = __float2bfloat16(h); \
    } \
    asm volatile("s_waitcnt lgkmcnt(0)" ::: "memory"); \
    __builtin_amdgcn_s_barrier(); \
    t += dt; }

    for (int blk = 0; blk < T_ / 4; ++blk) {
        int base = blk * 4 + 4;
        int s0 = base     > T_ - 1 ? T_ - 1 : base;
        int s1 = base + 1 > T_ - 1 ? T_ - 1 : base + 1;
        int s2 = base + 2 > T_ - 1 ? T_ - 1 : base + 2;
        int s3 = base + 3 > T_ - 1 ? T_ - 1 : base + 3;
        uint2 nxt0 = XPLD(s0), nxt1 = XPLD(s1), nxt2 = XPLD(s2), nxt3 = XPLD(s3);

        STEP(0, cur0)
        STEP(1, cur1)
        STEP(0, cur2)
        STEP(1, cur3)

        cur0 = nxt0; cur1 = nxt1; cur2 = nxt2; cur3 = nxt3;
    }
#undef STEP
#undef DOT1
#undef XPLD
}

// ---------------------------------------------------------------------------
// K3: bf16 MFMA mixer. out[m][n] = hs[m].mixer_w[n] + mb[n], fp32 out.
// Same skeleton as K1; A already bf16; no permute.
// ---------------------------------------------------------------------------
__global__ __launch_bounds__(256) void mixer_mfma(
    const __hip_bfloat16* __restrict__ hs,   // [M][256] bf16
    const float* __restrict__ mw,            // [256][256] fp32
    const float* __restrict__ mb,
    float* __restrict__ out)                 // [M][256] fp32
{
    const int n0 = blockIdx.x * 64;
    const int m0 = blockIdx.y * 64;

    __shared__ alignas(16) unsigned short Asm[64 * 64];
    __shared__ alignas(16) unsigned short Bsm[64 * 64];
    __shared__ alignas(16) float Dlds[64 * 64];
    __shared__ float bias_s[64];

    const int tid = threadIdx.x;
    const int wv  = tid >> 6;
    const int ln  = tid & 63;
    const int wr  = (wv >> 1) * 32;
    const int wc  = (wv & 1) * 32;
    const int l15 = ln & 15;
    const int l4  = ln >> 4;

#define STAGE_A3(c2, k0) { int row = (c2) >> 3, kc = (c2) & 7; \
    uint4 v = *reinterpret_cast<const uint4*>(hs + (size_t)(m0 + row) * 256 + (k0) + kc * 8); \
    *reinterpret_cast<uint4*>(reinterpret_cast<char*>(Asm) + row * 128 + ((kc * 16) ^ ((row & 7) << 4))) = v; }
#define STAGE_B3(c2, k0) { int row = (c2) >> 3, kc = (c2) & 7; \
    const float4* sp = reinterpret_cast<const float4*>(mw + (size_t)(n0 + row) * 256 + (k0) + kc * 8); \
    float4 fa = sp[0], fb = sp[1]; \
    u16x8 pk; pk[0]=f2bf(fa.x); pk[1]=f2bf(fa.y); pk[2]=f2bf(fa.z); pk[3]=f2bf(fa.w); \
    pk[4]=f2bf(fb.x); pk[5]=f2bf(fb.y); pk[6]=f2bf(fb.z); pk[7]=f2bf(fb.w); \
    *reinterpret_cast<u16x8*>(reinterpret_cast<char*>(Bsm) + row * 128 + ((kc * 16) ^ ((row & 7) << 4))) = pk; }

    STAGE_A3(tid, 0)  STAGE_A3(tid + 256, 0)
    STAGE_B3(tid, 0)  STAGE_B3(tid + 256, 0)
    if (tid < 64) bias_s[tid] = mb[n0 + tid];
    __syncthreads();

    const float bv0 = bias_s[wc + l15];
    const float bv1 = bias_s[wc + 16 + l15];
    f32x4 acc00 = {bv0, bv0, bv0, bv0};
    f32x4 acc01 = {bv1, bv1, bv1, bv1};
    f32x4 acc10 = {bv0, bv0, bv0, bv0};
    f32x4 acc11 = {bv1, bv1, bv1, bv1};

    const int ra0 = wr + l15,      ra1 = wr + 16 + l15;
    const int rb0 = wc + l15,      rb1 = wc + 16 + l15;

    for (int kst = 0; kst < 4; ++kst) {
        if (kst) {
            __syncthreads();
            STAGE_A3(tid, kst * 64)  STAGE_A3(tid + 256, kst * 64)
            STAGE_B3(tid, kst * 64)  STAGE_B3(tid + 256, kst * 64)
            __syncthreads();
        }
        #pragma unroll
        for (int ks = 0; ks < 64; ks += 32) {
            int kb = ks * 2 + (l4 << 4);
            bf16x8 a0 = FRAG(Asm, ra0, kb);
            bf16x8 a1 = FRAG(Asm, ra1, kb);
            bf16x8 b0 = FRAG(Bsm, rb0, kb);
            bf16x8 b1 = FRAG(Bsm, rb1, kb);
            acc00 = __builtin_amdgcn_mfma_f32_16x16x32_bf16(a0, b0, acc00, 0, 0, 0);
            acc01 = __builtin_amdgcn_mfma_f32_16x16x32_bf16(a0, b1, acc01, 0, 0, 0);
            acc10 = __builtin_amdgcn_mfma_f32_16x16x32_bf16(a1, b0, acc10, 0, 0, 0);
            acc11 = __builtin_amdgcn_mfma_f32_16x16x32_bf16(a1, b1, acc11, 0, 0, 0);
        }
    }
    __syncthreads();

#define DWRITE3(accv, mi, ni) { int row = wr + (mi) * 16 + l4 * 4; int col = wc + (ni) * 16 + l15; \
    Dlds[(row + 0) * 64 + col] = accv[0]; Dlds[(row + 1) * 64 + col] = accv[1]; \
    Dlds[(row + 2) * 64 + col] = accv[2]; Dlds[(row + 3) * 64 + col] = accv[3]; }
    DWRITE3(acc00, 0, 0) DWRITE3(acc01, 0, 1) DWRITE3(acc10, 1, 0) DWRITE3(acc11, 1, 1)
#undef DWRITE3
    __syncthreads();

    #pragma unroll
    for (int p = 0; p < 4; ++p) {
        int c2 = tid + p * 256;
        int row = c2 >> 4, ch = c2 & 15;
        float4 v = *reinterpret_cast<const float4*>(Dlds + row * 64 + ch * 4);
        *reinterpret_cast<float4*>(out + (size_t)(m0 + row) * 256 + n0 + ch * 4) = v;
    }
#undef STAGE_A3
#undef STAGE_B3
#undef FRAG
}

// ---------------------------------------------------------------------------
extern "C" void kernel_launch(void* const* d_in, const int* in_sizes, int n_in,
                              void* d_out, int out_size, void* d_ws, size_t ws_size,
                              hipStream_t stream) {
    const float* x       = (const float*)d_in[0];
    const float* w_ih_f  = (const float*)d_in[1];
    const float* w_hh_f  = (const float*)d_in[2];
    const float* b_ih_f  = (const float*)d_in[3];
    const float* b_hh_f  = (const float*)d_in[4];
    const float* w_ih_b  = (const float*)d_in[5];
    const float* w_hh_b  = (const float*)d_in[6];
    const float* b_ih_b  = (const float*)d_in[7];
    const float* b_hh_b  = (const float*)d_in[8];
    const float* mixer_w = (const float*)d_in[9];
    const float* mixer_b = (const float*)d_in[10];
    float* out = (float*)d_out;

    const size_t xp_bytes = (size_t)2 * M_ * G_ * sizeof(__hip_bfloat16); // 256 MiB
    const size_t hs_bytes = (size_t)M_ * 2 * H_ * sizeof(__hip_bfloat16); //  64 MiB
    if (ws_size < xp_bytes + hs_bytes) return;

    __hip_bfloat16* xp = (__hip_bfloat16*)d_ws;
    __hip_bfloat16* hs = (__hip_bfloat16*)((char*)d_ws + xp_bytes);

    gemm_in_mfma<<<dim3(16, M_ / 64), 256, 0, stream>>>(
        x, w_ih_f, w_ih_b, b_ih_f, b_hh_f, b_ih_b, b_hh_b, xp);
    lstm_rec<<<128, 512, 0, stream>>>(xp, w_hh_f, w_hh_b, hs);
    mixer_mfma<<<dim3(4, M_ / 64), 256, 0, stream>>>(
        hs, mixer_w, mixer_b, out);
}